// Round 4
// baseline (138.960 us; speedup 1.0000x reference)
//
#include <hip/hip_runtime.h>

// ContrasPQ forward = per-(b,p) nearest-code lookup.
// out[b, p*8 .. p*8+7] = codebook[p, argmin_k ||v[b,p]-c[p,k]||^2, :]
//
// R3/R4: argmin d2 == argmax g, g_k = sum_d c_kd*v_d - 0.5*||c_k||^2
// (monotone affine in d2 for fixed v; strict-> over ascending k == ref
// first-index tie-break). Multiply coefficients are the RAW codebook ->
// streamed over the idle SCALAR pipe (s_load_dwordx16, wave-uniform address)
// and consumed as the 1-allowed-SGPR operand of v_fmac_f32. LDS keeps only
// the per-k bias h = -0.5*||c||^2 (FMA-chain init must be a VGPR), read as
// 2 broadcast b128 per 8 codes. LDS pipe load drops 12x; VALU is the sole
// remaining limiter at ~23 instrs/k for 2 queries.
//
// R2 post-mortem: 6 blocks/CU fixed occupancy but only bought 4% -> LDS pipe
// (18.4K broadcast ds_reads/CU through one LDS unit shared by 4 SIMDs) was
// co-limiting with VALU at ~50% each.
// R3 post-mortem: macro had // comments eating the line-continuation
// backslashes -> brace mismatch. Rewritten as template<int LO> helper.

#define TPB 256   // threads per block
#define KBQ 2     // queries (b rows) per thread
#define CHUNK 8   // codes per SGPR-resident chunk (64 data SGPRs)

typedef float sf16 __attribute__((ext_vector_type(16)));

namespace {
constexpr int kB   = 8192;
constexpr int kEMB = 768;
constexpr int kP   = 96;
constexpr int kK   = 256;
constexpr int kD   = 8;
}

// One code (8 coefs at sf16 elements LO..LO+7) vs KBQ queries.
// Strict >: ties keep lower k (matches ref argmax first-index).
template <int LO>
__device__ __forceinline__ void pq_code(const sf16& blk, float h, int kk,
                                        const float (&v)[KBQ][kD],
                                        float (&best)[KBQ], int (&bidx)[KBQ])
{
#pragma unroll
    for (int q = 0; q < KBQ; ++q) {
        float g = fmaf(blk[LO + 0], v[q][0], h);
        g = fmaf(blk[LO + 1], v[q][1], g);
        g = fmaf(blk[LO + 2], v[q][2], g);
        g = fmaf(blk[LO + 3], v[q][3], g);
        g = fmaf(blk[LO + 4], v[q][4], g);
        g = fmaf(blk[LO + 5], v[q][5], g);
        g = fmaf(blk[LO + 6], v[q][6], g);
        g = fmaf(blk[LO + 7], v[q][7], g);
        if (g > best[q]) {
            best[q] = g;
            bidx[q] = kk;
        }
    }
}

__global__ __launch_bounds__(TPB, 6)
void pq_argmin_kernel(const float* __restrict__ vecs,
                      const float* __restrict__ codebook,
                      float* __restrict__ out)
{
    __shared__ alignas(16) float lds_h[kK];   // -0.5 * ||c_k||^2

    const int p = blockIdx.y;
    const int t = threadIdx.x;

    // ---- stage bias only: thread t handles code t (coalesced) ----
    {
        const float4* cb4 =
            reinterpret_cast<const float4*>(codebook + (size_t)p * kK * kD);
        float4 a = cb4[2 * t];
        float4 b = cb4[2 * t + 1];
        float c2 = a.x * a.x + a.y * a.y + a.z * a.z + a.w * a.w +
                   b.x * b.x + b.y * b.y + b.z * b.z + b.w * b.w;
        lds_h[t] = -0.5f * c2;
    }
    __syncthreads();

    // ---- load KBQ query subvectors (8 floats each, 2x float4) ----
    const int b0 = blockIdx.x * (TPB * KBQ) + t;

    float v[KBQ][kD];
#pragma unroll
    for (int q = 0; q < KBQ; ++q) {
        const float4* vp = reinterpret_cast<const float4*>(
            vecs + (size_t)(b0 + q * TPB) * kEMB + p * kD);
        float4 x = vp[0];
        float4 y = vp[1];
        v[q][0] = x.x; v[q][1] = x.y; v[q][2] = x.z; v[q][3] = x.w;
        v[q][4] = y.x; v[q][5] = y.y; v[q][6] = y.z; v[q][7] = y.w;
    }

    float best[KBQ];
    int   bidx[KBQ];
#pragma unroll
    for (int q = 0; q < KBQ; ++q) {
        best[q] = -__builtin_inff();   // maximizing g now
        bidx[q] = 0;
    }

    // ---- main loop: 32 chunks x 8 codes, coefs via scalar pipe ----
    const float* cbp = codebook + (size_t)p * kK * kD;  // wave-uniform

    for (int c = 0; c < kK / CHUNK; ++c) {
        sf16 sA, sB, sC, sD;  // 64 floats = codes c*8 .. c*8+7
        asm volatile("s_load_dwordx16 %0, %1, 0x0"  : "=s"(sA) : "s"(cbp));
        asm volatile("s_load_dwordx16 %0, %1, 0x40" : "=s"(sB) : "s"(cbp));
        asm volatile("s_load_dwordx16 %0, %1, 0x80" : "=s"(sC) : "s"(cbp));
        asm volatile("s_load_dwordx16 %0, %1, 0xc0" : "=s"(sD) : "s"(cbp));

        // bias for these 8 codes: 2 broadcast b128 reads (VGPR-resident, as
        // required for the FMA-chain init operand)
        const float4 h0 = *reinterpret_cast<const float4*>(&lds_h[c * CHUNK]);
        const float4 h1 = *reinterpret_cast<const float4*>(&lds_h[c * CHUNK + 4]);
        const float hh[CHUNK] = {h0.x, h0.y, h0.z, h0.w,
                                 h1.x, h1.y, h1.z, h1.w};

        asm volatile("s_waitcnt lgkmcnt(0)" ::: "memory");
        __builtin_amdgcn_sched_barrier(0);   // rule #18: pin FMAs after wait

        const int kbase = c * CHUNK;
        pq_code<0>(sA, hh[0], kbase + 0, v, best, bidx);
        pq_code<8>(sA, hh[1], kbase + 1, v, best, bidx);
        pq_code<0>(sB, hh[2], kbase + 2, v, best, bidx);
        pq_code<8>(sB, hh[3], kbase + 3, v, best, bidx);
        pq_code<0>(sC, hh[4], kbase + 4, v, best, bidx);
        pq_code<8>(sC, hh[5], kbase + 5, v, best, bidx);
        pq_code<0>(sD, hh[6], kbase + 6, v, best, bidx);
        pq_code<8>(sD, hh[7], kbase + 7, v, best, bidx);

        cbp += CHUNK * kD;
    }

    // ---- epilogue: gather winning codebook rows (L2-hot) and store ----
#pragma unroll
    for (int q = 0; q < KBQ; ++q) {
        const float4* cr = reinterpret_cast<const float4*>(
            codebook + ((size_t)p * kK + bidx[q]) * kD);
        float4 r0 = cr[0];
        float4 r1 = cr[1];
        float4* op = reinterpret_cast<float4*>(
            out + (size_t)(b0 + q * TPB) * kEMB + p * kD);
        op[0] = r0;
        op[1] = r1;
    }
}

extern "C" void kernel_launch(void* const* d_in, const int* in_sizes, int n_in,
                              void* d_out, int out_size, void* d_ws, size_t ws_size,
                              hipStream_t stream)
{
    const float* vecs     = (const float*)d_in[0];
    const float* codebook = (const float*)d_in[1];
    float* out            = (float*)d_out;

    dim3 grid(kB / (TPB * KBQ), kP, 1);  // (16, 96)
    dim3 block(TPB, 1, 1);
    hipLaunchKernelGGL(pq_argmin_kernel, grid, block, 0, stream,
                       vecs, codebook, out);
}

// Round 9
// 131.812 us; speedup vs baseline: 1.0542x; 1.0542x over previous
//
#include <hip/hip_runtime.h>

// ContrasPQ forward = per-(b,p) nearest-code lookup.
// out[b, p*8 .. p*8+7] = codebook[p, argmin_k ||v[b,p]-c[p,k]||^2, :]
//
// R8/R9: MFMA shortlist + EXACT fp32 rescore.
//   Stage 1 (matrix pipe): approx scores g~ = (vh+vm).(ch+cm) - 0.5||c||^2
//     via ONE mfma_f32_16x16x32_bf16 per 16-code tile (2-term bf16 split,
//     A groups [vh,vh,vm,vm] x B groups [ch,cm,ch,cm]).
//     |g~ - g| <= E ~ 3e-4 (dropped cross terms 2^-17*sum|v||c| +
//     MFMA f32 tree-accumulation rounding).
//   Stage 2 (VALU, rare): flag codes with g~ >= M - THR (THR=2e-3 >= 2E;
//     provably includes every code whose EXACT score ties/beats the max),
//     rescore flagged codes with the exact f32 op sequence (fmaf chain
//     ascending dims from h=-0.5||c||^2) and pick strict-max / lowest-k.
//     This f32-chain family benched absmax=0.0 on all 786K cells (R0/R2/R4).
//
// R6/R7 post-mortem: absmax 0.908 << 1.99 => only ~1-2 wrong cells =>
// layouts and plumbing are CORRECT; failure was near-tie cells whose top-2
// gap sits below the ~1e-6 MFMA accumulation noise (uncontrollable). Hence:
// keep MFMA for the heavy lifting, make the *decision* exact on the VALU.
// R8: container infra failure (no compile/run). Resubmitted unchanged after
// re-audit (rescore soundness, LDS bijection, DPP row containment checked).
//
// Layouts (HW-verified lineage): A row = lane&15, B col = lane&15,
// (lane-group,elem)->k bijection shared by A/B (m97 ref-checked GEMM);
// C/D col=lane&15, row=(lane>>4)*4+reg (m89/m91 asymmetric-verified).

typedef float f32x4  __attribute__((ext_vector_type(4)));
typedef short bf16x8 __attribute__((ext_vector_type(8)));

namespace {
constexpr int kB   = 8192;
constexpr int kEMB = 768;
constexpr int kP   = 96;
constexpr int kK   = 256;
constexpr int kD   = 8;
constexpr int QPB  = 64;   // queries per block (4 waves x 16)
}

#define PQ_THR 2.0e-3f     // flag threshold >= 2*E

// Manual RN-even f32->bf16 (headerless; data has no NaN/inf).
__device__ __forceinline__ short bf16_rn(float x)
{
    unsigned u = __float_as_uint(x);
    unsigned r = u + 0x7FFFu + ((u >> 16) & 1u);
    return (short)(r >> 16);
}
__device__ __forceinline__ float bf16_f32(short s)
{
    return __uint_as_float(((unsigned)(unsigned short)s) << 16);
}

// Butterfly max/min over each 16-lane group (quad xor1, xor2, then
// half-mirror / mirror == xor4 / xor8 once quads/halves are uniform).
__device__ __forceinline__ float dpp_max16(float x)
{
    int y;
    y = __builtin_amdgcn_update_dpp(__float_as_int(x), __float_as_int(x),
                                    0xB1, 0xF, 0xF, true);
    x = fmaxf(x, __int_as_float(y));
    y = __builtin_amdgcn_update_dpp(__float_as_int(x), __float_as_int(x),
                                    0x4E, 0xF, 0xF, true);
    x = fmaxf(x, __int_as_float(y));
    y = __builtin_amdgcn_update_dpp(__float_as_int(x), __float_as_int(x),
                                    0x141, 0xF, 0xF, true);
    x = fmaxf(x, __int_as_float(y));
    y = __builtin_amdgcn_update_dpp(__float_as_int(x), __float_as_int(x),
                                    0x140, 0xF, 0xF, true);
    x = fmaxf(x, __int_as_float(y));
    return x;
}

__device__ __forceinline__ int dpp_min16(int x)
{
    int y;
    y = __builtin_amdgcn_update_dpp(x, x, 0xB1, 0xF, 0xF, true);
    x = min(x, y);
    y = __builtin_amdgcn_update_dpp(x, x, 0x4E, 0xF, 0xF, true);
    x = min(x, y);
    y = __builtin_amdgcn_update_dpp(x, x, 0x141, 0xF, 0xF, true);
    x = min(x, y);
    y = __builtin_amdgcn_update_dpp(x, x, 0x140, 0xF, 0xF, true);
    x = min(x, y);
    return x;
}

// Flag + exact-rescore + cross-lane pick for query (group base + I).
// Returns the winning code index, uniform across the 16-lane group.
template <int I>
__device__ __forceinline__ int rescore_pick(float Mi, const f32x4 (&acc)[16],
                                            int colq, const float* vq,
                                            const float* code_f,
                                            const float* h_f)
{
    float bs = -__builtin_inff();
    int   bk = 1024;                      // sentinel > any real k
#pragma unroll
    for (int m = 0; m < 16; ++m) {
        const float a = acc[m][I];        // biased approx score
        if (a >= Mi - PQ_THR) {
            const int kc = m * 16 + colq;
            const float* cr = &code_f[kc * kD];
            // EXACT f32 score (reference-matching chain):
            float s = fmaf(cr[0], vq[0], h_f[kc]);
            s = fmaf(cr[1], vq[1], s);
            s = fmaf(cr[2], vq[2], s);
            s = fmaf(cr[3], vq[3], s);
            s = fmaf(cr[4], vq[4], s);
            s = fmaf(cr[5], vq[5], s);
            s = fmaf(cr[6], vq[6], s);
            s = fmaf(cr[7], vq[7], s);
            if (s > bs) {                 // strict >, ascending m: lowest k
                bs = s;
                bk = kc;
            }
        }
    }
    const float S = dpp_max16(bs);
    return dpp_min16((bs == S) ? bk : 1024);
}

__global__ __launch_bounds__(256, 4)
void pq_mfma_kernel(const float* __restrict__ vecs,
                    const float* __restrict__ codebook,
                    float* __restrict__ out)
{
    // B fragments: [tile 16][grp 4][col 16][8 bf16] = 16 KB
    __shared__ alignas(16) short lds_B[16 * 512];
    __shared__ alignas(16) float lds_code[kK * kD];  // raw codes, 8 KB
    __shared__ alignas(16) float lds_h[kK];          // -0.5*||c||^2, 1 KB
    __shared__ alignas(16) float lds_v[QPB][kD];     // raw queries, 2 KB

    const int p = blockIdx.y;
    const int t = threadIdx.x;
    const int l = t & 63;
    const int colq = l & 15;   // A row / B col / C col within tile
    const int hi   = l >> 4;   // k-block term group
    const int w    = t >> 6;   // wave id

    // ---- stage codebook[p]: thread t <-> code t (coalesced) ----
    {
        const f32x4* cb4 =
            reinterpret_cast<const f32x4*>(codebook + (size_t)p * kK * kD);
        f32x4 ca = cb4[2 * t];
        f32x4 cbv = cb4[2 * t + 1];
        float cc[8] = {ca.x, ca.y, ca.z, ca.w, cbv.x, cbv.y, cbv.z, cbv.w};
        bf16x8 ph, pm;
        float c2 = 0.0f;
#pragma unroll
        for (int j = 0; j < 8; ++j) {
            float x  = cc[j];
            short h  = bf16_rn(x);
            short m_ = bf16_rn(x - bf16_f32(h));
            ph[j] = h; pm[j] = m_;
            c2 = fmaf(x, x, c2);
        }
        lds_h[t] = -0.5f * c2;
        f32x4* rc = reinterpret_cast<f32x4*>(&lds_code[t * kD]);
        rc[0] = ca;
        rc[1] = cbv;
        const int tile = t >> 4, col = t & 15;
        short* bp = &lds_B[tile * 512 + col * 8];
        // B terms per k-group: [ch, cm, ch, cm]
        *reinterpret_cast<bf16x8*>(bp + 0 * 128) = ph;
        *reinterpret_cast<bf16x8*>(bp + 1 * 128) = pm;
        *reinterpret_cast<bf16x8*>(bp + 2 * 128) = ph;
        *reinterpret_cast<bf16x8*>(bp + 3 * 128) = pm;
    }

    // ---- A fragments: wave w handles queries qbase..qbase+15 ----
    const int qrow = blockIdx.x * QPB + w * 16 + colq;
    bf16x8 a0;
    {
        const float* vp = vecs + (size_t)qrow * kEMB + p * kD;
        f32x4 va = *reinterpret_cast<const f32x4*>(vp);
        f32x4 vb = *reinterpret_cast<const f32x4*>(vp + 4);
        if (hi == 0) {   // one copy of each query's raw v into LDS
            f32x4* rv = reinterpret_cast<f32x4*>(&lds_v[w * 16 + colq][0]);
            rv[0] = va;
            rv[1] = vb;
        }
        float vv[8] = {va.x, va.y, va.z, va.w, vb.x, vb.y, vb.z, vb.w};
#pragma unroll
        for (int j = 0; j < 8; ++j) {
            float x  = vv[j];
            short h  = bf16_rn(x);
            short m_ = bf16_rn(x - bf16_f32(h));
            // A terms per k-group: [vh, vh, vm, vm]
            a0[j] = (hi < 2) ? h : m_;
        }
    }

    __syncthreads();

    // ---- 16 tiles x 1 MFMA: approx scores, 16 queries x 256 codes ----
    f32x4 acc[16];
    const f32x4 z4 = {0.0f, 0.0f, 0.0f, 0.0f};
    const short* bbase = &lds_B[l * 8];
#pragma unroll
    for (int m = 0; m < 16; ++m) {
        bf16x8 b0 = *reinterpret_cast<const bf16x8*>(bbase + m * 512);
        acc[m] = __builtin_amdgcn_mfma_f32_16x16x32_bf16(a0, b0, z4, 0, 0, 0);
    }

    // ---- add bias, per-lane running max over tiles ----
    const float NEG = -__builtin_inff();
    float M0 = NEG, M1 = NEG, M2 = NEG, M3 = NEG;
#pragma unroll
    for (int m = 0; m < 16; ++m) {
        const float hm = lds_h[m * 16 + colq];   // code k = m*16+colq
        acc[m].x += hm; acc[m].y += hm; acc[m].z += hm; acc[m].w += hm;
        M0 = fmaxf(M0, acc[m].x);
        M1 = fmaxf(M1, acc[m].y);
        M2 = fmaxf(M2, acc[m].z);
        M3 = fmaxf(M3, acc[m].w);
    }
    M0 = dpp_max16(M0); M1 = dpp_max16(M1);
    M2 = dpp_max16(M2); M3 = dpp_max16(M3);

    // ---- exact rescore of flagged candidates, per query row ----
    const float* vq0 = &lds_v[w * 16 + hi * 4 + 0][0];
    const float* vq1 = &lds_v[w * 16 + hi * 4 + 1][0];
    const float* vq2 = &lds_v[w * 16 + hi * 4 + 2][0];
    const float* vq3 = &lds_v[w * 16 + hi * 4 + 3][0];
    const int k0 = rescore_pick<0>(M0, acc, colq, vq0, lds_code, lds_h);
    const int k1 = rescore_pick<1>(M1, acc, colq, vq1, lds_code, lds_h);
    const int k2 = rescore_pick<2>(M2, acc, colq, vq2, lds_code, lds_h);
    const int k3 = rescore_pick<3>(M3, acc, colq, vq3, lds_code, lds_h);

    // ---- epilogue: lanes 0..7 of each group write its 4 queries ----
    if (colq < 8) {
        const int ka = (colq & 2) ? k1 : k0;
        const int kb = (colq & 2) ? k3 : k2;
        const int kq = (colq & 4) ? kb : ka;
        const int row = blockIdx.x * QPB + w * 16 + (hi << 2) + (colq >> 1);
        const f32x4* cr = reinterpret_cast<const f32x4*>(
            codebook + ((size_t)p * kK + kq) * kD) + (colq & 1);
        f32x4* op = reinterpret_cast<f32x4*>(
            out + (size_t)row * kEMB + p * kD) + (colq & 1);
        *op = *cr;
    }
}

extern "C" void kernel_launch(void* const* d_in, const int* in_sizes, int n_in,
                              void* d_out, int out_size, void* d_ws, size_t ws_size,
                              hipStream_t stream)
{
    const float* vecs     = (const float*)d_in[0];
    const float* codebook = (const float*)d_in[1];
    float* out            = (float*)d_out;

    dim3 grid(kB / QPB, kP, 1);   // (128, 96)
    dim3 block(256, 1, 1);
    hipLaunchKernelGGL(pq_mfma_kernel, grid, block, 0, stream,
                       vecs, codebook, out);
}